// Round 1
// baseline (1135.877 us; speedup 1.0000x reference)
//
#include <hip/hip_runtime.h>
#include <math.h>

#define VV 6
#define KK6 6
#define DD 32
#define CC 3
#define BB 64
#define NN 46656
#define EPSF 1e-5f

// ---- workspace layout (float offsets) ----
#define WS_PP    0          // P' [36][1024]
#define WS_C1    36864      // [1024]
#define WS_W2T   37888      // W2t [1024][256]
#define WS_C2    300032     // [256]
#define WS_W3T   300288     // W3t [256][784] (u' = hw*16+o)
#define WS_C3    500992     // [16]
#define WS_E1RAW 501008     // [64][256]
#define WS_E1N   517392     // [64][256]
#define WS_E2RAW 533776     // [64][1024]
#define WS_E2N   599312     // [64][1024]

#define OBS_SIZE (BB*NN)
#define DIST_OFF OBS_SIZE
#define LOSS_OFF (OBS_SIZE + BB*VV*KK6)

#define SMEM_FLOATS 18148
#define SMEM_BYTES  (SMEM_FLOATS*4)

// ============================ prep kernels ============================

__global__ void dvae_prep_p(const float* __restrict__ embeds, const float* __restrict__ dfc1_w,
                            const float* __restrict__ dfc1_b,
                            const float* __restrict__ g, const float* __restrict__ bt,
                            const float* __restrict__ rm, const float* __restrict__ rv,
                            float* __restrict__ Pp, float* __restrict__ c1) {
    int t = blockIdx.x * 256 + threadIdx.x;
    if (t >= 36 * 1024) return;
    int vk = t >> 10, j = t & 1023;
    int v = vk / 6;
    float s1 = g[j] * rsqrtf(rv[j] + EPSF);
    const float* e = embeds + vk * 32;
    const float* w = dfc1_w + j * 192 + v * 32;
    float acc = 0.f;
#pragma unroll
    for (int d = 0; d < 32; ++d) acc += e[d] * w[d];
    Pp[vk * 1024 + j] = s1 * acc;
    if (vk == 0) c1[j] = s1 * dfc1_b[j] + bt[j] - rm[j] * s1;
}

__global__ void dvae_prep_w2(const float* __restrict__ dfc2_w, const float* __restrict__ dfc2_b,
                             const float* __restrict__ g, const float* __restrict__ bt,
                             const float* __restrict__ rm, const float* __restrict__ rv,
                             float* __restrict__ W2t, float* __restrict__ c2) {
    int t = blockIdx.x * 256 + threadIdx.x;
    if (t >= 1024 * 256) return;
    int k = t >> 8, i = t & 255;
    float s2 = g[i] * rsqrtf(rv[i] + EPSF);
    W2t[t] = s2 * dfc2_w[i * 1024 + k];
    if (k == 0) c2[i] = s2 * dfc2_b[i] + bt[i] - rm[i] * s2;
}

__global__ void dvae_prep_w3(const float* __restrict__ dct1_w, const float* __restrict__ dct1_b,
                             const float* __restrict__ g, const float* __restrict__ bt,
                             const float* __restrict__ rm, const float* __restrict__ rv,
                             float* __restrict__ W3t, float* __restrict__ c3) {
    int t = blockIdx.x * 256 + threadIdx.x;
    if (t >= 256 * 784) return;
    int c = t / 784, r = t % 784;
    int hw = r >> 4, o = r & 15;
    float s3 = g[o] * rsqrtf(rv[o] + EPSF);
    W3t[t] = s3 * dct1_w[c * 784 + o * 49 + hw];
    if (t < 16) {
        float s = g[t] * rsqrtf(rv[t] + EPSF);
        c3[t] = s * dct1_b[t] + bt[t] - rm[t] * s;
    }
}

// ============================ encoder ============================

__global__ void dvae_enc_gemm1(const float* __restrict__ x, const float* __restrict__ w,
                               const float* __restrict__ b, float* __restrict__ out) {
    int t = blockIdx.x * 256 + threadIdx.x;
    if (t >= 64 * 256) return;
    int bb = t >> 8, o = t & 255;
    const float* xp = x + bb * 147;
    const float* wp = w + o * 147;
    float acc = b[o];
    for (int q = 0; q < 147; ++q) acc += xp[q] * wp[q];
    out[t] = acc;
}

__global__ void dvae_enc_bn(const float* __restrict__ in, const float* __restrict__ g,
                            const float* __restrict__ bt, float* __restrict__ out, int cols) {
    int o = blockIdx.x;
    int bb = threadIdx.x;  // 64 threads = 1 wave
    float v = in[bb * cols + o];
    float m = v;
#pragma unroll
    for (int s = 1; s < 64; s <<= 1) m += __shfl_xor(m, s);
    m *= (1.f / 64.f);
    float d = v - m;
    float var = d * d;
#pragma unroll
    for (int s = 1; s < 64; s <<= 1) var += __shfl_xor(var, s);
    var *= (1.f / 64.f);
    float y = g[o] * d * rsqrtf(var + EPSF) + bt[o];
    out[bb * cols + o] = fmaxf(y, 0.f);
}

__global__ void dvae_enc_gemm2(const float* __restrict__ in, const float* __restrict__ w,
                               const float* __restrict__ b, float* __restrict__ out) {
    int t = blockIdx.x * 256 + threadIdx.x;
    if (t >= 64 * 1024) return;
    int bb = t >> 10, j = t & 1023;
    const float* ip = in + bb * 256;
    const float* wp = w + j * 256;
    float acc = b[j];
    for (int q = 0; q < 256; ++q) acc += ip[q] * wp[q];
    out[t] = acc;
}

__global__ void dvae_enc_final(const float* __restrict__ e2n, const float* __restrict__ fc2_w,
                               const float* __restrict__ fc2_b, float* __restrict__ out) {
    __shared__ float sl[36];
    __shared__ float spart[6];
    int bb = blockIdx.x, t = threadIdx.x;
    if (t < 36) {
        const float* ip = e2n + bb * 1024;
        const float* wp = fc2_w + t * 1024;
        float acc = fc2_b[t];
        for (int q = 0; q < 1024; ++q) acc += ip[q] * wp[q];
        sl[t] = acc;
    }
    __syncthreads();
    if (t < 6) {
        float mx = -1e30f;
#pragma unroll
        for (int k = 0; k < 6; ++k) mx = fmaxf(mx, sl[t * 6 + k]);
        float s = 0.f, ex[6];
#pragma unroll
        for (int k = 0; k < 6; ++k) { ex[k] = expf(sl[t * 6 + k] - mx); s += ex[k]; }
        float inv = 1.f / s, part = 0.f;
#pragma unroll
        for (int k = 0; k < 6; ++k) {
            float dd = ex[k] * inv;
            out[DIST_OFF + bb * 36 + t * 6 + k] = dd;
            part += dd * logf(dd + 1e-10f);
        }
        spart[t] = part;
    }
    __syncthreads();
    if (t == 0) {
        float l = 0.f;
#pragma unroll
        for (int v = 0; v < 6; ++v) l += spart[v];
        out[LOSS_OFF + bb] = 0.1f * l;
    }
}

// ============================ fused decoder ============================
// One block = 32 codes (n). Phase 1: h2[32][256] = relu(h1 @ W2t + c2), h1 built
// from P' table gathers in K-chunks of 32. Phase 2: per 112-col u-chunk of W3t:
// h3 = relu(h2 @ W3t + c3), em = h3 proj, obs accumulation vs all 64 batch rows.

__launch_bounds__(256)
__global__ void dvae_decoder(const float* __restrict__ x, const float* __restrict__ Pp,
                             const float* __restrict__ c1, const float* __restrict__ W2t,
                             const float* __restrict__ c2, const float* __restrict__ W3t,
                             const float* __restrict__ c3, const float* __restrict__ dct2_w,
                             const float* __restrict__ dct2_b, float* __restrict__ out) {
    extern __shared__ float sm[];
    float* shH2t = sm;                 // [256][33] = 8448
    float* shSX2 = sm + 8448;          // [64]
    float* shSE2 = sm + 8512;          // [32]
    int*   shDig = (int*)(sm + 8544);  // [32][6] = 192
    float* shC3  = sm + 8736;          // [16]
    float* shD2w = sm + 8752;          // [48]
    float* shD2b = sm + 8800;          // [4]
    float* U     = sm + 8804;          // union region (9344 floats)
    float* shA  = U;                   // phase1: [32][36] = 1152
    float* shB  = U + 1152;            // phase1: [32][256] = 8192
    float* shW3 = U;                   // phase2: [32][112] = 3584
    float* shH3 = U + 3584;            // phase2: [32][113] = 3616
    float* shEm = U + 7200;            // phase2: [32][22]  = 704
    float* shXc = U + 7904;            // phase2: [64][22]  = 1408

    int tid = threadIdx.x;
    int nbase = blockIdx.x * 32;

    // init: digits, sum(x^2), small tables
    if (tid < 32) {
        int n = nbase + tid;
        int p = 7776;
#pragma unroll
        for (int v = 0; v < 6; ++v) { shDig[tid * 6 + v] = (n / p) % 6; p /= 6; }
    }
    if (tid < 64) {
        const float* xp = x + tid * 147;
        float s = 0.f;
        for (int q = 0; q < 147; ++q) { float t2 = xp[q]; s += t2 * t2; }
        shSX2[tid] = s;
    }
    if (tid < 16) shC3[tid] = c3[tid];
    if (tid < 48) shD2w[tid] = dct2_w[tid];
    if (tid < 3)  shD2b[tid] = dct2_b[tid];

    // ---------- phase 1: h2 = relu(h1 @ W2t + c2) ----------
    float acc1[32];
#pragma unroll
    for (int i = 0; i < 32; ++i) acc1[i] = 0.f;
    int ngrp = tid >> 5;            // 0..7
    int igrp = tid & 31;            // 0..31
    int n01 = ngrp * 4, i0 = igrp * 8;
    int an = tid >> 3;              // 0..31 (n for shA build)
    int jq = (tid & 7) * 4;         // j-quad within chunk

    for (int kc = 0; kc < 32; ++kc) {
        __syncthreads();
        {   // load W2t chunk -> shB [32][256]
            const float4* src = (const float4*)(W2t + kc * 8192);
            float4* dst = (float4*)shB;
#pragma unroll
            for (int i = 0; i < 8; ++i) dst[tid + i * 256] = src[tid + i * 256];
        }
        {   // build h1 chunk transposed -> shA[k][n]
            int j0 = kc * 32 + jq;
            float4 a = *(const float4*)(c1 + j0);
#pragma unroll
            for (int v = 0; v < 6; ++v) {
                int row = v * 6 + shDig[an * 6 + v];
                float4 p = *(const float4*)(Pp + row * 1024 + j0);
                a.x += p.x; a.y += p.y; a.z += p.z; a.w += p.w;
            }
            shA[(jq + 0) * 36 + an] = fmaxf(a.x, 0.f);
            shA[(jq + 1) * 36 + an] = fmaxf(a.y, 0.f);
            shA[(jq + 2) * 36 + an] = fmaxf(a.z, 0.f);
            shA[(jq + 3) * 36 + an] = fmaxf(a.w, 0.f);
        }
        __syncthreads();
#pragma unroll 4
        for (int k = 0; k < 32; ++k) {
            float4 av = *(const float4*)(shA + k * 36 + n01);
            float4 b0 = *(const float4*)(shB + k * 256 + i0);
            float4 b1 = *(const float4*)(shB + k * 256 + i0 + 4);
            float bv[8] = {b0.x, b0.y, b0.z, b0.w, b1.x, b1.y, b1.z, b1.w};
            float aa[4] = {av.x, av.y, av.z, av.w};
#pragma unroll
            for (int jn = 0; jn < 4; ++jn)
#pragma unroll
                for (int ji = 0; ji < 8; ++ji)
                    acc1[jn * 8 + ji] += aa[jn] * bv[ji];
        }
    }
    // epilogue: relu(+c2) -> shH2t[i][n]  (transposed, stride 33)
#pragma unroll
    for (int ji = 0; ji < 8; ++ji) {
        int i = i0 + ji;
        float cc = c2[i];
#pragma unroll
        for (int jn = 0; jn < 4; ++jn)
            shH2t[i * 33 + n01 + jn] = fmaxf(acc1[jn * 8 + ji] + cc, 0.f);
    }
    __syncthreads();

    // ---------- phase 2 ----------
    int ngrp2 = tid & 15;           // n0 = ngrp2*2
    int ugrp  = tid >> 4;           // u0 = ugrp*7 ; also b0 = ugrp*4
    int n02 = ngrp2 * 2, u0 = ugrp * 7;
    float accO[8];
#pragma unroll
    for (int i = 0; i < 8; ++i) accO[i] = 0.f;
    float sE2 = 0.f;

    for (int uc = 0; uc < 7; ++uc) {
        float acc2[14];
#pragma unroll
        for (int i = 0; i < 14; ++i) acc2[i] = 0.f;
        for (int kk = 0; kk < 8; ++kk) {
            __syncthreads();
            // load W3t slice rows kk*32..+32, cols uc*112..+112
#pragma unroll
            for (int i = 0; i < 14; ++i) {
                int e = tid + i * 256;
                int r = e / 112, cL = e % 112;
                shW3[e] = W3t[(kk * 32 + r) * 784 + uc * 112 + cL];
            }
            __syncthreads();
#pragma unroll 2
            for (int k = 0; k < 32; ++k) {
                int crow = (kk * 32 + k) * 33;
                float a0 = shH2t[crow + n02];
                float a1 = shH2t[crow + n02 + 1];
                const float* bp = shW3 + k * 112 + u0;
#pragma unroll
                for (int j = 0; j < 7; ++j) {
                    float bv = bp[j];
                    acc2[j]     += a0 * bv;
                    acc2[7 + j] += a1 * bv;
                }
            }
        }
        // h3 epilogue -> shH3[n][u_local], relu(+c3[o])
#pragma unroll
        for (int j = 0; j < 7; ++j) {
            int ul = u0 + j;
            float cc = shC3[ul & 15];
            shH3[n02 * 113 + ul]       = fmaxf(acc2[j] + cc, 0.f);
            shH3[(n02 + 1) * 113 + ul] = fmaxf(acc2[7 + j] + cc, 0.f);
        }
        // load x chunk -> shXc[b][oc*7+hl]
        for (int e = tid; e < 64 * 21; e += 256) {
            int bb = e / 21, r = e % 21;
            int oc = r / 7, hl = r % 7;
            shXc[bb * 22 + r] = x[bb * 147 + oc * 49 + uc * 7 + hl];
        }
        __syncthreads();
        // em phase: em[n][oc][hl]
        for (int e = tid; e < 32 * 21; e += 256) {
            int n = e / 21, r = e % 21;
            int oc = r / 7, hl = r % 7;
            const float* hp = shH3 + n * 113 + hl * 16;
            float acc = shD2b[oc];
#pragma unroll
            for (int o = 0; o < 16; ++o) acc += hp[o] * shD2w[o * 3 + oc];
            shEm[n * 22 + r] = acc;
        }
        __syncthreads();
        // sumE2 (one lane per n)
        if (tid < 32) {
            const float* ep = shEm + tid * 22;
#pragma unroll
            for (int r = 0; r < 21; ++r) sE2 += ep[r] * ep[r];
        }
        // obs accumulation: 2n x 4b per thread
        {
            const float* e0 = shEm + n02 * 22;
            const float* e1 = shEm + (n02 + 1) * 22;
            const float* xp0 = shXc + (ugrp * 4) * 22;
#pragma unroll
            for (int r = 0; r < 21; ++r) {
                float ea = e0[r], eb = e1[r];
#pragma unroll
                for (int jb = 0; jb < 4; ++jb) {
                    float xv = xp0[jb * 22 + r];
                    accO[jb * 2 + 0] += ea * xv;
                    accO[jb * 2 + 1] += eb * xv;
                }
            }
        }
    }

    // final write
    if (tid < 32) shSE2[tid] = sE2;
    __syncthreads();
    {
        int b0 = ugrp * 4;
        float h0 = 0.5f * shSE2[n02];
        float h1v = 0.5f * shSE2[n02 + 1];
#pragma unroll
        for (int jb = 0; jb < 4; ++jb) {
            int bb = b0 + jb;
            float base = -0.5f * shSX2[bb];
            float2 val;
            val.x = accO[jb * 2 + 0] - h0 + base;
            val.y = accO[jb * 2 + 1] - h1v + base;
            *(float2*)(out + (size_t)bb * NN + nbase + n02) = val;
        }
    }
}

// ============================ launcher ============================

extern "C" void kernel_launch(void* const* d_in, const int* in_sizes, int n_in,
                              void* d_out, int out_size, void* d_ws, size_t ws_size,
                              hipStream_t stream) {
    const float* x       = (const float*)d_in[0];
    const float* conv_w  = (const float*)d_in[1];
    const float* conv_b  = (const float*)d_in[2];
    const float* ebn2_g  = (const float*)d_in[3];
    const float* ebn2_b  = (const float*)d_in[4];
    const float* fc1_w   = (const float*)d_in[5];
    const float* fc1_b   = (const float*)d_in[6];
    const float* ebn1_g  = (const float*)d_in[7];
    const float* ebn1_b  = (const float*)d_in[8];
    const float* fc2_w   = (const float*)d_in[9];
    const float* fc2_b   = (const float*)d_in[10];
    const float* embeds  = (const float*)d_in[11];
    const float* dfc1_w  = (const float*)d_in[12];
    const float* dfc1_b  = (const float*)d_in[13];
    const float* dbn1_g  = (const float*)d_in[14];
    const float* dbn1_b  = (const float*)d_in[15];
    const float* dbn1_rm = (const float*)d_in[16];
    const float* dbn1_rv = (const float*)d_in[17];
    const float* dfc2_w  = (const float*)d_in[18];
    const float* dfc2_b  = (const float*)d_in[19];
    const float* dbn2_g  = (const float*)d_in[20];
    const float* dbn2_b  = (const float*)d_in[21];
    const float* dbn2_rm = (const float*)d_in[22];
    const float* dbn2_rv = (const float*)d_in[23];
    const float* dct1_w  = (const float*)d_in[24];
    const float* dct1_b  = (const float*)d_in[25];
    const float* dbn3_g  = (const float*)d_in[26];
    const float* dbn3_b  = (const float*)d_in[27];
    const float* dbn3_rm = (const float*)d_in[28];
    const float* dbn3_rv = (const float*)d_in[29];
    const float* dct2_w  = (const float*)d_in[30];
    const float* dct2_b  = (const float*)d_in[31];

    float* ws  = (float*)d_ws;
    float* out = (float*)d_out;

    // prep tables (independent)
    dvae_prep_p <<<144, 256, 0, stream>>>(embeds, dfc1_w, dfc1_b, dbn1_g, dbn1_b, dbn1_rm, dbn1_rv,
                                          ws + WS_PP, ws + WS_C1);
    dvae_prep_w2<<<1024, 256, 0, stream>>>(dfc2_w, dfc2_b, dbn2_g, dbn2_b, dbn2_rm, dbn2_rv,
                                           ws + WS_W2T, ws + WS_C2);
    dvae_prep_w3<<<784, 256, 0, stream>>>(dct1_w, dct1_b, dbn3_g, dbn3_b, dbn3_rm, dbn3_rv,
                                          ws + WS_W3T, ws + WS_C3);
    // encoder chain
    dvae_enc_gemm1<<<64, 256, 0, stream>>>(x, conv_w, conv_b, ws + WS_E1RAW);
    dvae_enc_bn   <<<256, 64, 0, stream>>>(ws + WS_E1RAW, ebn2_g, ebn2_b, ws + WS_E1N, 256);
    dvae_enc_gemm2<<<256, 256, 0, stream>>>(ws + WS_E1N, fc1_w, fc1_b, ws + WS_E2RAW);
    dvae_enc_bn   <<<1024, 64, 0, stream>>>(ws + WS_E2RAW, ebn1_g, ebn1_b, ws + WS_E2N, 1024);
    dvae_enc_final<<<64, 64, 0, stream>>>(ws + WS_E2N, fc2_w, fc2_b, out);
    // fused decoder (needs >64KB dynamic LDS)
    hipFuncSetAttribute(reinterpret_cast<const void*>(dvae_decoder),
                        hipFuncAttributeMaxDynamicSharedMemorySize, SMEM_BYTES);
    dvae_decoder<<<NN / 32, 256, SMEM_BYTES, stream>>>(x, ws + WS_PP, ws + WS_C1, ws + WS_W2T,
                                                       ws + WS_C2, ws + WS_W3T, ws + WS_C3,
                                                       dct2_w, dct2_b, out);
}

// Round 3
// 323.743 us; speedup vs baseline: 3.5086x; 3.5086x over previous
//
#include <hip/hip_runtime.h>
#include <math.h>

#define EPSF 1e-5f
#define NNC 46656

typedef __attribute__((ext_vector_type(4))) float  f32x4;
typedef __attribute__((ext_vector_type(8))) short  short8;
typedef __attribute__((ext_vector_type(8))) unsigned short ushort8;

__device__ __forceinline__ float bf2f(unsigned short u) {
    unsigned int x = ((unsigned int)u) << 16;
    return __builtin_bit_cast(float, x);
}
__device__ __forceinline__ unsigned short f2bf(float f) {
    unsigned int x = __builtin_bit_cast(unsigned int, f);
    unsigned int r = (x + 0x7fffu + ((x >> 16) & 1u)) >> 16;
    return (unsigned short)r;
}

// ---- workspace layout (float offsets) ----
// sizes: ushort arrays need count/2 floats (count*2 bytes)
#define WS_PP    0u          // P' [36][1024] f32                  36864
#define WS_C1    36864u      // [1024] f32                          1024
#define WS_SH    37888u      // Sh bf16 [216][1024] -> 110592 f
#define WS_SL    148480u     // Sl bf16 [36][1024]  -> 18432 f
#define WS_P5    166912u     // P5 bf16 [6][1024]   -> 3072 f
#define WS_W2BF  169984u     // W2 bf16 [256][1024] -> 131072 f
#define WS_C2    301056u     // [256] f32
#define WS_W3BF  301312u     // W3 bf16 [784][256]  -> 100352 f
#define WS_C3    401664u     // [16] f32
#define WS_XBF   401680u     // X bf16 [64][160]    -> 5120 f
#define WS_SX2   406800u     // [64] f32
#define WS_E1RAW 406864u     // [64][256] f32
#define WS_E1N   423248u
#define WS_E2RAW 439632u     // [64][1024] f32
#define WS_E2N   505168u
// total = 570704 floats ~= 2.28 MB

#define OBS_SIZE (64*NNC)
#define DIST_OFF OBS_SIZE
#define LOSS_OFF (OBS_SIZE + 64*36)

// ---- LDS layout (bytes) for decoder ----
#define L_C2   0      // f32[256]
#define L_C3   1024   // f32[16]
#define L_D2W  1088   // f32[48]
#define L_D2B  1280   // f32[4]
#define L_SX2  1296   // f32[64]
#define L_SE2P 1552   // f32[256]
#define L_SE2F 2576   // f32[64]
#define L_A    2848            // phase1 A bf16 [32 kb][64 m][8]  (32768 B)
#define L_EM   2848            // phase2/3 em bf16 [64][168]      (21504 B)
#define L_H3T  24352           // phase2 per-wave f32 [16][68] x4 (17408 B)
#define L_X    24352           // phase3 X bf16 [64][168]         (21504 B)
#define L_H2   45856           // h2 bf16 [32 kb][64 m][8]        (32768 B)
#define LDS_BYTES 78624

// ============================ prep kernels ============================

__global__ void dvae_prep_p(const float* __restrict__ embeds, const float* __restrict__ dfc1_w,
                            const float* __restrict__ dfc1_b,
                            const float* __restrict__ g, const float* __restrict__ bt,
                            const float* __restrict__ rm, const float* __restrict__ rv,
                            float* __restrict__ Pp, float* __restrict__ c1,
                            unsigned short* __restrict__ P5) {
    int t = blockIdx.x * 256 + threadIdx.x;
    if (t >= 36 * 1024) return;
    int vk = t >> 10, j = t & 1023;
    int v = vk / 6;
    float s1 = g[j] * rsqrtf(rv[j] + EPSF);
    const float* e = embeds + vk * 32;
    const float* w = dfc1_w + j * 192 + v * 32;
    float acc = 0.f;
#pragma unroll
    for (int d = 0; d < 32; ++d) acc += e[d] * w[d];
    float val = s1 * acc;
    Pp[vk * 1024 + j] = val;
    if (vk >= 30) P5[(vk - 30) * 1024 + j] = f2bf(val);
    if (vk == 0) c1[j] = s1 * dfc1_b[j] + bt[j] - rm[j] * s1;
}

// Sh[gh][j] = c1[j] + P'[d0][j] + P'[6+d1][j] + P'[12+d2][j], gh = d0*36+d1*6+d2
__global__ void dvae_prep_sh(const float* __restrict__ Pp, const float* __restrict__ c1,
                             unsigned short* __restrict__ Sh) {
    int t = blockIdx.x * 256 + threadIdx.x;
    if (t >= 216 * 128) return;
    int gh = t >> 7, kg = (t & 127) * 8;
    int d0 = gh / 36, d1 = (gh / 6) % 6, d2 = gh % 6;
    const float* r0 = Pp + d0 * 1024 + kg;
    const float* r1 = Pp + (6 + d1) * 1024 + kg;
    const float* r2 = Pp + (12 + d2) * 1024 + kg;
    const float* cc = c1 + kg;
    ushort8 o;
#pragma unroll
    for (int e = 0; e < 8; ++e) o[e] = f2bf(cc[e] + r0[e] + r1[e] + r2[e]);
    *(ushort8*)(Sh + gh * 1024 + kg) = o;
}

// Sl[gl][j] = P'[18+d3][j] + P'[24+d4][j], gl = d3*6+d4
__global__ void dvae_prep_sl(const float* __restrict__ Pp, unsigned short* __restrict__ Sl) {
    int t = blockIdx.x * 256 + threadIdx.x;
    if (t >= 36 * 128) return;
    int gl = t >> 7, kg = (t & 127) * 8;
    int d3 = gl / 6, d4 = gl % 6;
    const float* r3 = Pp + (18 + d3) * 1024 + kg;
    const float* r4 = Pp + (24 + d4) * 1024 + kg;
    ushort8 o;
#pragma unroll
    for (int e = 0; e < 8; ++e) o[e] = f2bf(r3[e] + r4[e]);
    *(ushort8*)(Sl + gl * 1024 + kg) = o;
}

__global__ void dvae_prep_w2(const float* __restrict__ dfc2_w, const float* __restrict__ dfc2_b,
                             const float* __restrict__ g, const float* __restrict__ bt,
                             const float* __restrict__ rm, const float* __restrict__ rv,
                             unsigned short* __restrict__ W2, float* __restrict__ c2) {
    int t = blockIdx.x * 256 + threadIdx.x;   // one float4 group
    if (t >= 256 * 256) return;
    int i = t >> 8, kq = (t & 255) * 4;
    float s2 = g[i] * rsqrtf(rv[i] + EPSF);
    float4 w = *(const float4*)(dfc2_w + i * 1024 + kq);
    unsigned short* dst = W2 + i * 1024 + kq;
    dst[0] = f2bf(s2 * w.x); dst[1] = f2bf(s2 * w.y);
    dst[2] = f2bf(s2 * w.z); dst[3] = f2bf(s2 * w.w);
    if (kq == 0) c2[i] = s2 * dfc2_b[i] + bt[i] - rm[i] * s2;
}

// W3[u'=hw*16+o][k] = s3[o] * dct1_w[k][o][hw]
__global__ void dvae_prep_w3(const float* __restrict__ dct1_w, const float* __restrict__ dct1_b,
                             const float* __restrict__ g, const float* __restrict__ bt,
                             const float* __restrict__ rm, const float* __restrict__ rv,
                             unsigned short* __restrict__ W3, float* __restrict__ c3) {
    int t = blockIdx.x * 256 + threadIdx.x;
    if (t >= 784 * 256) return;
    int up = t >> 8, k = t & 255;
    int o = up & 15, hw = up >> 4;
    float s3 = g[o] * rsqrtf(rv[o] + EPSF);
    W3[t] = f2bf(s3 * dct1_w[k * 784 + o * 49 + hw]);
    if (t < 16) {
        float s = g[t] * rsqrtf(rv[t] + EPSF);
        c3[t] = s * dct1_b[t] + bt[t] - rm[t] * s;
    }
}

// Xb[b][hw*3+c] = x[b][c][hw] (bf16, cols 147..159 zero), sx2[b] = ||x_b||^2
__global__ void dvae_prep_x(const float* __restrict__ x, unsigned short* __restrict__ Xb,
                            float* __restrict__ sx2) {
    int tid = threadIdx.x;
    if (tid < 64) {
        const float* xp = x + tid * 147;
        float s = 0.f;
        for (int qq = 0; qq < 147; ++qq) { float v = xp[qq]; s += v * v; }
        sx2[tid] = s;
    }
    for (int e = tid; e < 64 * 160; e += 256) {
        int b = e / 160, col = e % 160;
        float v = 0.f;
        if (col < 147) {
            int hw = col / 3, c = col % 3;
            v = x[b * 147 + c * 49 + hw];
        }
        Xb[e] = f2bf(v);
    }
}

// ============================ encoder ============================

__global__ void dvae_enc_gemm1(const float* __restrict__ x, const float* __restrict__ w,
                               const float* __restrict__ b, float* __restrict__ out) {
    int t = blockIdx.x * 256 + threadIdx.x;
    if (t >= 64 * 256) return;
    int bb = t >> 8, o = t & 255;
    const float* xp = x + bb * 147;
    const float* wp = w + o * 147;
    float acc = b[o];
    for (int qq = 0; qq < 147; ++qq) acc += xp[qq] * wp[qq];
    out[t] = acc;
}

__global__ void dvae_enc_bn(const float* __restrict__ in, const float* __restrict__ g,
                            const float* __restrict__ bt, float* __restrict__ out, int cols) {
    int o = blockIdx.x;
    int bb = threadIdx.x;
    float v = in[bb * cols + o];
    float m = v;
#pragma unroll
    for (int s = 1; s < 64; s <<= 1) m += __shfl_xor(m, s);
    m *= (1.f / 64.f);
    float d = v - m;
    float var = d * d;
#pragma unroll
    for (int s = 1; s < 64; s <<= 1) var += __shfl_xor(var, s);
    var *= (1.f / 64.f);
    float y = g[o] * d * rsqrtf(var + EPSF) + bt[o];
    out[bb * cols + o] = fmaxf(y, 0.f);
}

__global__ void dvae_enc_gemm2(const float* __restrict__ in, const float* __restrict__ w,
                               const float* __restrict__ b, float* __restrict__ out) {
    int t = blockIdx.x * 256 + threadIdx.x;
    if (t >= 64 * 1024) return;
    int bb = t >> 10, j = t & 1023;
    const float* ip = in + bb * 256;
    const float* wp = w + j * 256;
    float acc = b[j];
    for (int qq = 0; qq < 256; ++qq) acc += ip[qq] * wp[qq];
    out[t] = acc;
}

__global__ void dvae_enc_final(const float* __restrict__ e2n, const float* __restrict__ fc2_w,
                               const float* __restrict__ fc2_b, float* __restrict__ out) {
    __shared__ float sl[36];
    __shared__ float spart[6];
    int bb = blockIdx.x, t = threadIdx.x;
    if (t < 36) {
        const float* ip = e2n + bb * 1024;
        const float* wp = fc2_w + t * 1024;
        float acc = fc2_b[t];
        for (int qq = 0; qq < 1024; ++qq) acc += ip[qq] * wp[qq];
        sl[t] = acc;
    }
    __syncthreads();
    if (t < 6) {
        float mx = -1e30f;
#pragma unroll
        for (int k = 0; k < 6; ++k) mx = fmaxf(mx, sl[t * 6 + k]);
        float s = 0.f, ex[6];
#pragma unroll
        for (int k = 0; k < 6; ++k) { ex[k] = expf(sl[t * 6 + k] - mx); s += ex[k]; }
        float inv = 1.f / s, part = 0.f;
#pragma unroll
        for (int k = 0; k < 6; ++k) {
            float dd = ex[k] * inv;
            out[DIST_OFF + bb * 36 + t * 6 + k] = dd;
            part += dd * logf(dd + 1e-10f);
        }
        spart[t] = part;
    }
    __syncthreads();
    if (t == 0) {
        float l = 0.f;
#pragma unroll
        for (int v = 0; v < 6; ++v) l += spart[v];
        out[LOSS_OFF + bb] = 0.1f * l;
    }
}

// ============================ fused MFMA decoder ============================
// Block = 64 codes, 256 threads (4 waves).
// P1: h1 built in LDS from Sh/Sl/P5 (bf16), GEMM2 via mfma 16x16x32 (B from L2),
//     h2 -> LDS bf16 in A-frag layout.
// P2: GEMM3 vs W3 (B from L2), per-wave channel projection -> em bf16 in LDS.
// P3: obs = X @ em^T via mfma, minus 0.5*||E||^2, 0.5*||X||^2.

__launch_bounds__(256, 2)
__global__ void dvae_decoder(const unsigned short* __restrict__ Sh,
                             const unsigned short* __restrict__ Sl,
                             const unsigned short* __restrict__ P5,
                             const unsigned short* __restrict__ W2,
                             const float* __restrict__ c2g,
                             const unsigned short* __restrict__ W3,
                             const float* __restrict__ c3g,
                             const float* __restrict__ d2wg,
                             const float* __restrict__ d2bg,
                             const unsigned short* __restrict__ Xg,
                             const float* __restrict__ sx2g,
                             float* __restrict__ out) {
    extern __shared__ char sm[];
    float* c2s  = (float*)(sm + L_C2);
    float* c3s  = (float*)(sm + L_C3);
    float* d2ws = (float*)(sm + L_D2W);
    float* d2bs = (float*)(sm + L_D2B);
    float* sx2s = (float*)(sm + L_SX2);
    float* sE2p = (float*)(sm + L_SE2P);
    float* sE2f = (float*)(sm + L_SE2F);
    unsigned short* Albs = (unsigned short*)(sm + L_A);
    unsigned short* emL  = (unsigned short*)(sm + L_EM);
    float*          h3Tb = (float*)(sm + L_H3T);
    unsigned short* XL   = (unsigned short*)(sm + L_X);
    unsigned short* h2L  = (unsigned short*)(sm + L_H2);

    int tid = threadIdx.x;
    int wv = tid >> 6, lane = tid & 63, l15 = lane & 15, q = lane >> 4;
    int nbase = blockIdx.x * 64;

    c2s[tid] = c2g[tid];
    if (tid < 16) c3s[tid] = c3g[tid];
    if (tid < 48) d2ws[tid] = d2wg[tid];
    if (tid < 4) d2bs[tid] = (tid < 3) ? d2bg[tid] : 0.f;
    if (tid < 64) sx2s[tid] = sx2g[tid];

    // ---------------- phase 1: GEMM2 ----------------
    f32x4 acc[4][4];
#pragma unroll
    for (int a = 0; a < 4; ++a)
#pragma unroll
        for (int b = 0; b < 4; ++b) acc[a][b] = (f32x4){0.f, 0.f, 0.f, 0.f};

    int mB = tid >> 2, sub = tid & 3;
    int nm = nbase + mB;
    int gh = nm / 216;
    int rem = nm - gh * 216;
    int gl = rem / 6;
    int d5 = rem - gl * 6;
    const unsigned short* shp = Sh + gh * 1024;
    const unsigned short* slp = Sl + gl * 1024;
    const unsigned short* p5p = P5 + d5 * 1024;

    for (int kc = 0; kc < 4; ++kc) {
        __syncthreads();
        int kbase = kc * 256;
        // build h1 chunk (bf16) -> Albs [kb][m][8]
#pragma unroll
        for (int t = 0; t < 8; ++t) {
            int gg = sub * 8 + t;
            int k = kbase + gg * 8;
            ushort8 hv = *(const ushort8*)(shp + k);
            ushort8 lv = *(const ushort8*)(slp + k);
            ushort8 pv = *(const ushort8*)(p5p + k);
            ushort8 o;
#pragma unroll
            for (int e = 0; e < 8; ++e) {
                float f = bf2f(hv[e]) + bf2f(lv[e]) + bf2f(pv[e]);
                o[e] = f2bf(fmaxf(f, 0.f));
            }
            *(ushort8*)(Albs + (gg * 64 + mB) * 8) = o;
        }
        __syncthreads();
        // MFMA: wave wv owns i in [wv*64, wv*64+64)
        const unsigned short* bbase = W2 + (wv * 64 + l15) * 1024 + kbase + q * 8;
        short8 bpre[4];
#pragma unroll
        for (int j = 0; j < 4; ++j) bpre[j] = *(const short8*)(bbase + j * 16384);
#pragma unroll
        for (int s = 0; s < 8; ++s) {
            short8 bcur[4];
#pragma unroll
            for (int j = 0; j < 4; ++j) bcur[j] = bpre[j];
            if (s < 7) {
#pragma unroll
                for (int j = 0; j < 4; ++j)
                    bpre[j] = *(const short8*)(bbase + j * 16384 + (s + 1) * 32);
            }
            short8 af[4];
#pragma unroll
            for (int mt = 0; mt < 4; ++mt)
                af[mt] = *(const short8*)(Albs + ((s * 4 + q) * 64 + mt * 16 + l15) * 8);
#pragma unroll
            for (int mt = 0; mt < 4; ++mt)
#pragma unroll
                for (int j = 0; j < 4; ++j)
                    acc[mt][j] = __builtin_amdgcn_mfma_f32_16x16x32_bf16(af[mt], bcur[j], acc[mt][j], 0, 0, 0);
        }
    }
    // h2 epilogue -> h2L bf16 [kb=i>>3][m][i&7]
#pragma unroll
    for (int mt = 0; mt < 4; ++mt) {
#pragma unroll
        for (int j = 0; j < 4; ++j) {
            int i = wv * 64 + j * 16 + l15;
            float cc = c2s[i];
#pragma unroll
            for (int r = 0; r < 4; ++r) {
                int m = mt * 16 + q * 4 + r;
                float v = fmaxf(acc[mt][j][r] + cc, 0.f);
                h2L[((i >> 3) * 64 + m) * 8 + (i & 7)] = f2bf(v);
            }
        }
    }
    __syncthreads();

    // ---------------- phase 2: GEMM3 + channel projection ----------------
    float sE2a = 0.f;
    float* h3w = h3Tb + wv * 1088;   // per-wave [16][68] f32
    for (int c = wv; c < 13; c += 4) {
        int hw0 = c * 4;
        f32x4 a2[4][4];
#pragma unroll
        for (int a = 0; a < 4; ++a)
#pragma unroll
            for (int b = 0; b < 4; ++b) a2[a][b] = (f32x4){0.f, 0.f, 0.f, 0.f};
        const unsigned short* b3[4];
#pragma unroll
        for (int j = 0; j < 4; ++j) {
            int hw = hw0 + j; if (hw > 48) hw = 48;
            b3[j] = W3 + (hw * 16 + l15) * 256 + q * 8;
        }
        short8 bpre[4];
#pragma unroll
        for (int j = 0; j < 4; ++j) bpre[j] = *(const short8*)(b3[j]);
#pragma unroll
        for (int s = 0; s < 8; ++s) {
            short8 bcur[4];
#pragma unroll
            for (int j = 0; j < 4; ++j) bcur[j] = bpre[j];
            if (s < 7) {
#pragma unroll
                for (int j = 0; j < 4; ++j) bpre[j] = *(const short8*)(b3[j] + (s + 1) * 32);
            }
            short8 af[4];
#pragma unroll
            for (int mt = 0; mt < 4; ++mt)
                af[mt] = *(const short8*)(h2L + ((s * 4 + q) * 64 + mt * 16 + l15) * 8);
#pragma unroll
            for (int mt = 0; mt < 4; ++mt)
#pragma unroll
                for (int j = 0; j < 4; ++j)
                    a2[mt][j] = __builtin_amdgcn_mfma_f32_16x16x32_bf16(af[mt], bcur[j], a2[mt][j], 0, 0, 0);
        }
        // per-hw epilogue (wave-private)
#pragma unroll
        for (int j = 0; j < 4; ++j) {
            int hw = hw0 + j;
            if (hw <= 48) {
#pragma unroll
                for (int mt = 0; mt < 4; ++mt) {
#pragma unroll
                    for (int r = 0; r < 4; ++r) {
                        int m = mt * 16 + q * 4 + r;
                        h3w[l15 * 68 + m] = fmaxf(a2[mt][j][r] + c3s[l15], 0.f);
                    }
                }
                // em for m = lane (all 64 m in this wave)
                float e0 = d2bs[0], e1 = d2bs[1], e2 = d2bs[2];
#pragma unroll
                for (int o = 0; o < 16; ++o) {
                    float h = h3w[o * 68 + lane];
                    e0 += h * d2ws[o * 3 + 0];
                    e1 += h * d2ws[o * 3 + 1];
                    e2 += h * d2ws[o * 3 + 2];
                }
                unsigned short u0 = f2bf(e0), u1 = f2bf(e1), u2 = f2bf(e2);
                float f0 = bf2f(u0), f1 = bf2f(u1), f2v = bf2f(u2);
                sE2a += f0 * f0 + f1 * f1 + f2v * f2v;
                emL[lane * 168 + hw * 3 + 0] = u0;
                emL[lane * 168 + hw * 3 + 1] = u1;
                emL[lane * 168 + hw * 3 + 2] = u2;
            }
        }
    }
    sE2p[wv * 64 + lane] = sE2a;
    __syncthreads();

    // finalize sE2, zero em tail, stage X
    if (tid < 64) sE2f[tid] = sE2p[tid] + sE2p[64 + tid] + sE2p[128 + tid] + sE2p[192 + tid];
    for (int e = tid; e < 64 * 13; e += 256) {
        int m = e / 13, col = 147 + (e % 13);
        emL[m * 168 + col] = 0;
    }
    for (int e = tid; e < 1280; e += 256) {
        int b = e / 20, gg = e % 20;
        *(ushort8*)(XL + b * 168 + gg * 8) = *(const ushort8*)(Xg + b * 160 + gg * 8);
    }
    __syncthreads();

    // ---------------- phase 3: obs = X @ em^T ----------------
    f32x4 aO[4];
#pragma unroll
    for (int j = 0; j < 4; ++j) aO[j] = (f32x4){0.f, 0.f, 0.f, 0.f};
    const unsigned short* xrow = XL + (wv * 16 + l15) * 168 + q * 8;
#pragma unroll
    for (int s = 0; s < 5; ++s) {
        short8 af = *(const short8*)(xrow + s * 32);
#pragma unroll
        for (int j = 0; j < 4; ++j) {
            short8 bfv = *(const short8*)(emL + (j * 16 + l15) * 168 + s * 32 + q * 8);
            aO[j] = __builtin_amdgcn_mfma_f32_16x16x32_bf16(af, bfv, aO[j], 0, 0, 0);
        }
    }
#pragma unroll
    for (int j = 0; j < 4; ++j) {
        int n = nbase + j * 16 + l15;
        float he = 0.5f * sE2f[j * 16 + l15];
#pragma unroll
        for (int r = 0; r < 4; ++r) {
            int b = wv * 16 + q * 4 + r;
            out[(size_t)b * NNC + n] = aO[j][r] - he - 0.5f * sx2s[b];
        }
    }
}

// ============================ launcher ============================

extern "C" void kernel_launch(void* const* d_in, const int* in_sizes, int n_in,
                              void* d_out, int out_size, void* d_ws, size_t ws_size,
                              hipStream_t stream) {
    const float* x       = (const float*)d_in[0];
    const float* conv_w  = (const float*)d_in[1];
    const float* conv_b  = (const float*)d_in[2];
    const float* ebn2_g  = (const float*)d_in[3];
    const float* ebn2_b  = (const float*)d_in[4];
    const float* fc1_w   = (const float*)d_in[5];
    const float* fc1_b   = (const float*)d_in[6];
    const float* ebn1_g  = (const float*)d_in[7];
    const float* ebn1_b  = (const float*)d_in[8];
    const float* fc2_w   = (const float*)d_in[9];
    const float* fc2_b   = (const float*)d_in[10];
    const float* embeds  = (const float*)d_in[11];
    const float* dfc1_w  = (const float*)d_in[12];
    const float* dfc1_b  = (const float*)d_in[13];
    const float* dbn1_g  = (const float*)d_in[14];
    const float* dbn1_b  = (const float*)d_in[15];
    const float* dbn1_rm = (const float*)d_in[16];
    const float* dbn1_rv = (const float*)d_in[17];
    const float* dfc2_w  = (const float*)d_in[18];
    const float* dfc2_b  = (const float*)d_in[19];
    const float* dbn2_g  = (const float*)d_in[20];
    const float* dbn2_b  = (const float*)d_in[21];
    const float* dbn2_rm = (const float*)d_in[22];
    const float* dbn2_rv = (const float*)d_in[23];
    const float* dct1_w  = (const float*)d_in[24];
    const float* dct1_b  = (const float*)d_in[25];
    const float* dbn3_g  = (const float*)d_in[26];
    const float* dbn3_b  = (const float*)d_in[27];
    const float* dbn3_rm = (const float*)d_in[28];
    const float* dbn3_rv = (const float*)d_in[29];
    const float* dct2_w  = (const float*)d_in[30];
    const float* dct2_b  = (const float*)d_in[31];

    float* ws  = (float*)d_ws;
    float* out = (float*)d_out;

    unsigned short* P5  = (unsigned short*)(ws + WS_P5);
    unsigned short* Sh  = (unsigned short*)(ws + WS_SH);
    unsigned short* Sl  = (unsigned short*)(ws + WS_SL);
    unsigned short* W2b = (unsigned short*)(ws + WS_W2BF);
    unsigned short* W3b = (unsigned short*)(ws + WS_W3BF);
    unsigned short* Xb  = (unsigned short*)(ws + WS_XBF);

    // prep tables
    dvae_prep_p <<<144, 256, 0, stream>>>(embeds, dfc1_w, dfc1_b, dbn1_g, dbn1_b, dbn1_rm, dbn1_rv,
                                          ws + WS_PP, ws + WS_C1, P5);
    dvae_prep_sh<<<108, 256, 0, stream>>>(ws + WS_PP, ws + WS_C1, Sh);
    dvae_prep_sl<<<18, 256, 0, stream>>>(ws + WS_PP, Sl);
    dvae_prep_w2<<<256, 256, 0, stream>>>(dfc2_w, dfc2_b, dbn2_g, dbn2_b, dbn2_rm, dbn2_rv,
                                          W2b, ws + WS_C2);
    dvae_prep_w3<<<784, 256, 0, stream>>>(dct1_w, dct1_b, dbn3_g, dbn3_b, dbn3_rm, dbn3_rv,
                                          W3b, ws + WS_C3);
    dvae_prep_x <<<1, 256, 0, stream>>>(x, Xb, ws + WS_SX2);

    // encoder chain
    dvae_enc_gemm1<<<64, 256, 0, stream>>>(x, conv_w, conv_b, ws + WS_E1RAW);
    dvae_enc_bn   <<<256, 64, 0, stream>>>(ws + WS_E1RAW, ebn2_g, ebn2_b, ws + WS_E1N, 256);
    dvae_enc_gemm2<<<256, 256, 0, stream>>>(ws + WS_E1N, fc1_w, fc1_b, ws + WS_E2RAW);
    dvae_enc_bn   <<<1024, 64, 0, stream>>>(ws + WS_E2RAW, ebn1_g, ebn1_b, ws + WS_E2N, 1024);
    dvae_enc_final<<<64, 64, 0, stream>>>(ws + WS_E2N, fc2_w, fc2_b, out);

    // fused MFMA decoder
    hipFuncSetAttribute(reinterpret_cast<const void*>(dvae_decoder),
                        hipFuncAttributeMaxDynamicSharedMemorySize, LDS_BYTES);
    dvae_decoder<<<NNC / 64, 256, LDS_BYTES, stream>>>(Sh, Sl, P5, W2b, ws + WS_C2, W3b, ws + WS_C3,
                                                       dct2_w, dct2_b, Xb, ws + WS_SX2, out);
}